// Round 3
// baseline (291.239 us; speedup 1.0000x reference)
//
#include <hip/hip_runtime.h>
#include <hip/hip_fp16.h>

// ModulatedDeformConv (DCNv2) — f16 MFMA version, occupancy-focused.
// B=4, C=128, H=W=128, Cout=128, DG=8 (Cg=16), 3x3, stride=1, pad=1, dil=1.
//
// prep wconv:  weight fp32 [o][c*9+k] -> f16 [o][g*144 + k*16 + cg]
//              (K-permutation shared with the sampled operand).
// prep xtrans: x fp32 (B,C,H,W) -> f16 x_t (B,DG,H,W,Cg): one bilinear
//              corner = one aligned 32B read.
// dcn_main:    per block 16 output positions x 128 couts. CK split into two
//              g-halves of 576 -> LDS tile 16x584 f16 = 18.7 KB -> 8
//              blocks/CU (100% occupancy). Phase 1: packed-f16 bilinear into
//              LDS (col order [gl][k][cg]: k-stride = 8 banks, conflict-free).
//              Phase 2: mfma_f32_16x16x32_f16, acc carried across halves.

#define NB    4
#define NC    128
#define NH    128
#define NW    128
#define NCOUT 128
#define NDG   8
#define NCG   16
#define NK    9
#define NCK   1152
#define NHW   16384
#define TP    16
#define HCK   576            // columns per half
#define LDROW 584            // f16 elems per LDS row per half (1168 B)

typedef __attribute__((ext_vector_type(4))) float f32x4;
typedef _Float16 half8 __attribute__((ext_vector_type(8)));

// ---- prep A: weight fp32 [o][c*9+k] -> f16 [o][g*144+k*16+cg] ----
__global__ __launch_bounds__(256)
void wconv(const float* __restrict__ w, ushort* __restrict__ wf) {
  const int t = blockIdx.x * 256 + threadIdx.x;   // 73728 = 128 o * 576 u32
  const int o   = t / HCK;
  const int r   = t - o * HCK;       // r = g*72 + k*8 + cg/2
  const int g   = r / 72;
  const int r2  = r - g * 72;
  const int k   = r2 >> 3;
  const int c   = g * NCG + (r2 & 7) * 2;
  const ushort h0 = __half_as_ushort(__float2half_rn(w[o * NCK + c * NK + k]));
  const ushort h1 = __half_as_ushort(__float2half_rn(w[o * NCK + (c + 1) * NK + k]));
  ((unsigned*)wf)[t] = (unsigned)h0 | ((unsigned)h1 << 16);
}

// ---- prep B: x fp32 (B,C,H,W) -> f16 x_t (B,DG,H,W,Cg), 2 rows/block ----
__global__ __launch_bounds__(256)
void xtrans(const float* __restrict__ x, ushort* __restrict__ xt) {
  __shared__ ushort T[256 * 17];                  // [h*128+w][c], pad 17
  const int blk = blockIdx.x;                     // b*512 + g*64 + h2
  const int h2 = blk & 63;
  const int g  = (blk >> 6) & 7;
  const int b  = blk >> 9;
  const int tid = threadIdx.x;
  const float* xb = x + (size_t)(b * NC + g * NCG) * NHW + h2 * 2 * NW;
#pragma unroll
  for (int i = 0; i < 4; ++i) {
    const int lin = tid + 256 * i;                // 0..1023 float4 tasks
    const int w4  = lin & 31;
    const int h   = (lin >> 5) & 1;
    const int c   = lin >> 6;                     // 0..15
    const float4 v = *(const float4*)(xb + c * NHW + h * NW + w4 * 4);
    ushort* tp = &T[(h * NW + w4 * 4) * 17 + c];
    tp[0]      = __half_as_ushort(__float2half_rn(v.x));
    tp[17]     = __half_as_ushort(__float2half_rn(v.y));
    tp[34]     = __half_as_ushort(__float2half_rn(v.z));
    tp[51]     = __half_as_ushort(__float2half_rn(v.w));
  }
  __syncthreads();
  ushort* dst = xt + ((size_t)(b * NDG + g) * NHW + h2 * 2 * NW) * NCG;
#pragma unroll
  for (int i = 0; i < 2; ++i) {
    const int lin = tid + 256 * i;                // 0..511 uint4 tasks
    const int hw  = lin >> 1;
    const int c0  = (lin & 1) * 8;
    const ushort* s = &T[hw * 17 + c0];
    uint4 u;
    u.x = (unsigned)s[0] | ((unsigned)s[1] << 16);
    u.y = (unsigned)s[2] | ((unsigned)s[3] << 16);
    u.z = (unsigned)s[4] | ((unsigned)s[5] << 16);
    u.w = (unsigned)s[6] | ((unsigned)s[7] << 16);
    *(uint4*)(dst + hw * NCG + c0) = u;
  }
}

// ---- main ----
union C16 { uint4 u[2]; __half2 h[8]; };

__global__ __launch_bounds__(256, 8)
void dcn_main(const float* __restrict__ off,
              const float* __restrict__ msk,
              const ushort* __restrict__ xt,   // f16 (B,DG,H,W,Cg)
              const ushort* __restrict__ wt,   // f16 [o][g*144+k*16+cg]
              const float* __restrict__ bias,
              float* __restrict__ out) {
  __shared__ __align__(16) ushort S[TP * LDROW];   // 18,688 B

  const int tid  = threadIdx.x;
  const int pos0 = blockIdx.x * TP;
  const int b    = pos0 >> 14;
  const int ho   = (pos0 >> 7) & 127;
  const int wo0  = pos0 & 127;

  const int lane = tid & 63;
  const int wv   = tid >> 6;
  const int row  = lane & 15;
  const int kq   = lane >> 4;

  f32x4 acc0 = {0.f, 0.f, 0.f, 0.f};
  f32x4 acc1 = {0.f, 0.f, 0.f, 0.f};

  for (int hf = 0; hf < 2; ++hf) {
    if (hf) __syncthreads();                 // phase-2(h0) done reading S

    // ---- Phase 1: sample half hf -> S[p][gl*144 + k*16 + cg] ----
    for (int t = tid; t < TP * 4 * NK; t += 256) {   // 576 tasks
      const int p   = t & 15;
      const int gkl = t >> 4;                // 0..35
      const int gl  = gkl / 9;
      const int k   = gkl - gl * 9;
      const int g   = hf * 4 + gl;
      const int gk  = g * 9 + k;
      const int ky  = k / 3, kx = k - ky * 3;
      const int wo  = wo0 + p;
      const int sp  = ho * NW + wo;

      const float dy = off[(b * 144 + gk * 2) * NHW + sp];
      const float dx = off[(b * 144 + gk * 2 + 1) * NHW + sp];
      const float m  = msk[(b * 72 + gk) * NHW + sp];

      const float sy = dy + (float)(ho - 1 + ky);
      const float sx = dx + (float)(wo - 1 + kx);
      const float y0f = floorf(sy), x0f = floorf(sx);
      const float ly = sy - y0f, lx = sx - x0f;
      const int y0 = (int)y0f, x0 = (int)x0f;
      const int y1 = y0 + 1,  x1 = x0 + 1;
      const float hy = 1.f - ly, hx = 1.f - lx;

      float w00 = hy * hx * m, w01 = hy * lx * m;
      float w10 = ly * hx * m, w11 = ly * lx * m;
      if (y0 < 0 || y0 >= NH) { w00 = 0.f; w01 = 0.f; }
      if (y1 < 0 || y1 >= NH) { w10 = 0.f; w11 = 0.f; }
      if (x0 < 0 || x0 >= NW) { w00 = 0.f; w10 = 0.f; }
      if (x1 < 0 || x1 >= NW) { w01 = 0.f; w11 = 0.f; }

      const int yc0 = min(max(y0, 0), NH - 1);
      const int yc1 = min(max(y1, 0), NH - 1);
      const int xc0 = min(max(x0, 0), NW - 1);
      const int xc1 = min(max(x1, 0), NW - 1);

      const ushort* xg = xt + (size_t)(b * NDG + g) * NHW * NCG;
      const uint4* q00 = (const uint4*)(xg + (yc0 * NW + xc0) * NCG);
      const uint4* q01 = (const uint4*)(xg + (yc0 * NW + xc1) * NCG);
      const uint4* q10 = (const uint4*)(xg + (yc1 * NW + xc0) * NCG);
      const uint4* q11 = (const uint4*)(xg + (yc1 * NW + xc1) * NCG);

      C16 v00, v01, v10, v11, r;
      v00.u[0] = q00[0]; v00.u[1] = q00[1];
      v01.u[0] = q01[0]; v01.u[1] = q01[1];
      v10.u[0] = q10[0]; v10.u[1] = q10[1];
      v11.u[0] = q11[0]; v11.u[1] = q11[1];

      const __half2 W00 = __float2half2_rn(w00);
      const __half2 W01 = __float2half2_rn(w01);
      const __half2 W10 = __float2half2_rn(w10);
      const __half2 W11 = __float2half2_rn(w11);
#pragma unroll
      for (int i = 0; i < 8; ++i) {
        __half2 a = __hmul2(v00.h[i], W00);
        a = __hfma2(v01.h[i], W01, a);
        a = __hfma2(v10.h[i], W10, a);
        a = __hfma2(v11.h[i], W11, a);
        r.h[i] = a;
      }
      ushort* dstp = &S[p * LDROW + gl * 144 + k * 16];
      *(uint4*)dstp = r.u[0];
      *((uint4*)dstp + 1) = r.u[1];
    }
    __syncthreads();

    // ---- Phase 2: MFMA over this half's K=576 ----
    const ushort* arow = &S[row * LDROW + kq * 8];
    const ushort* b0 = wt + (size_t)(wv * 32 + row) * NCK + hf * HCK + kq * 8;
    const ushort* b1 = b0 + 16 * NCK;
#pragma unroll
    for (int kk = 0; kk < HCK; kk += 32) {
      half8 a  = *(const half8*)(arow + kk);
      half8 w0 = *(const half8*)(b0 + kk);
      half8 w1 = *(const half8*)(b1 + kk);
      acc0 = __builtin_amdgcn_mfma_f32_16x16x32_f16(a, w0, acc0, 0, 0, 0);
      acc1 = __builtin_amdgcn_mfma_f32_16x16x32_f16(a, w1, acc1, 0, 0, 0);
    }
  }

  // C/D: col = lane&15 = cout_local, row = (lane>>4)*4 + reg = pos
  const int c0 = wv * 32 + row;
  const float bs0 = bias[c0];
  const float bs1 = bias[c0 + 16];
  float* op0 = out + (size_t)(b * NCOUT + c0) * NHW + ho * NW + wo0 + kq * 4;
  float* op1 = op0 + 16 * NHW;
  float4 r0 = {acc0[0] + bs0, acc0[1] + bs0, acc0[2] + bs0, acc0[3] + bs0};
  float4 r1 = {acc1[0] + bs1, acc1[1] + bs1, acc1[2] + bs1, acc1[3] + bs1};
  *(float4*)op0 = r0;
  *(float4*)op1 = r1;
}

extern "C" void kernel_launch(void* const* d_in, const int* in_sizes, int n_in,
                              void* d_out, int out_size, void* d_ws, size_t ws_size,
                              hipStream_t stream) {
  const float* x    = (const float*)d_in[0];
  const float* off  = (const float*)d_in[1];
  const float* msk  = (const float*)d_in[2];
  const float* wgt  = (const float*)d_in[3];
  const float* bias = (const float*)d_in[4];
  float* out = (float*)d_out;

  ushort* xt = (ushort*)d_ws;                         // 16,777,216 B
  ushort* wf = xt + (size_t)NB * NDG * NHW * NCG;     // +294,912 B

  hipLaunchKernelGGL(wconv,  dim3(288),  dim3(256), 0, stream, wgt, wf);
  hipLaunchKernelGGL(xtrans, dim3(NB * NDG * 64), dim3(256), 0, stream, x, xt);
  hipLaunchKernelGGL(dcn_main, dim3((NB * NH * NW) / TP), dim3(256), 0, stream,
                     off, msk, xt, wf, bias, out);
}

// Round 4
// 203.985 us; speedup vs baseline: 1.4277x; 1.4277x over previous
//
#include <hip/hip_runtime.h>
#include <hip/hip_fp16.h>

// ModulatedDeformConv (DCNv2) — f16 MFMA, M=64 tile, weight-amortized.
// B=4, C=128, H=W=128, Cout=128, DG=8 (Cg=16), 3x3, stride=1, pad=1, dil=1.
//
// prep (ONE kernel): blocks 0-127: weight fp32 [o][c*9+k] -> f16
//   [o][(g*9+k)*16+cg]; blocks 128-639: x fp32 (B,C,H,W) -> f16
//   x_t (B,DG,H,W,Cg) via LDS transpose (conflict-free stride-9 u32 rows).
// dcn_main: 1024 blocks, 256 thr. Tile M=64 positions x N=128 couts,
//   K=1152 in 4 chunks of 288 (2 deform groups). Per chunk: sample
//   S[64][288] f16 into LDS (row stride 296 f16 -> even bank spread),
//   then 9 x mfma_f32_16x16x32_f16 steps; each wave: 4 M-subtiles x
//   2 N-subtiles (W lines read once per block -> 4x fewer than M=16).

#define NB    4
#define NC    128
#define NH    128
#define NW    128
#define NCOUT 128
#define NDG   8
#define NCG   16
#define NK    9
#define NCK   1152
#define NHW   16384
#define TP    64
#define BKC   288
#define ROWP  296            // padded S row stride in f16 (592 B)

typedef __attribute__((ext_vector_type(4))) float f32x4;
typedef _Float16 half8 __attribute__((ext_vector_type(8)));

union C16 { uint4 u[2]; __half2 h[8]; };

// ---------------- fused prep ----------------
__global__ __launch_bounds__(256)
void prep(const float* __restrict__ x, const float* __restrict__ w,
          ushort* __restrict__ xt, ushort* __restrict__ wf) {
  __shared__ __align__(16) unsigned LDSU[1024 * 9];   // 36,864 B
  const int tid = threadIdx.x;

  if (blockIdx.x < 128) {
    // ---- weight permute: [o][c*9+k] -> [o][(g*9+k)*16+cg] (f16) ----
    const int o = blockIdx.x;
    float* WL = (float*)LDSU;                          // 1152 floats
    const float4* src = (const float4*)(w + o * NCK);
    for (int i = tid; i < NCK / 4; i += 256) ((float4*)WL)[i] = src[i];
    __syncthreads();
    unsigned* dst = (unsigned*)wf + o * (NCK / 2);
    for (int t = tid; t < NCK / 2; t += 256) {
      const int g = t / 72, r2 = t - g * 72;
      const int k = r2 >> 3, cg2 = r2 & 7;
      const int c = g * NCG + cg2 * 2;
      const unsigned h0 = __half_as_ushort(__float2half_rn(WL[c * NK + k]));
      const unsigned h1 = __half_as_ushort(__float2half_rn(WL[(c + 1) * NK + k]));
      dst[t] = h0 | (h1 << 16);
    }
  } else {
    // ---- x transpose: (B,C,H,W) fp32 -> (B,DG,H,W,Cg) f16 ----
    const int blk  = blockIdx.x - 128;                 // 0..511
    const int slab = blk >> 4;                         // b*8+g
    const int hw0  = (blk & 15) * 1024;
    const float* xb = x + (size_t)slab * NCG * NHW + hw0;
#pragma unroll
    for (int cp = 0; cp < 8; ++cp) {
#pragma unroll
      for (int i = 0; i < 4; ++i) {
        const int hw = tid + 256 * i;
        const float f0 = xb[(2 * cp) * NHW + hw];
        const float f1 = xb[(2 * cp + 1) * NHW + hw];
        const unsigned h0 = __half_as_ushort(__float2half_rn(f0));
        const unsigned h1 = __half_as_ushort(__float2half_rn(f1));
        LDSU[hw * 9 + cp] = h0 | (h1 << 16);           // stride 9: conflict-free
      }
    }
    __syncthreads();
    uint4* dst = (uint4*)(xt + ((size_t)slab * NHW + hw0) * NCG);
#pragma unroll
    for (int j = 0; j < 8; ++j) {
      const int lin = tid + 256 * j;
      const int hw = lin >> 1, q = lin & 1;
      uint4 v;
      v.x = LDSU[hw * 9 + q * 4 + 0];
      v.y = LDSU[hw * 9 + q * 4 + 1];
      v.z = LDSU[hw * 9 + q * 4 + 2];
      v.w = LDSU[hw * 9 + q * 4 + 3];
      dst[lin] = v;                                    // 4 KB contiguous/wave-iter
    }
  }
}

// ---------------- main ----------------
__global__ __launch_bounds__(256, 4)
void dcn_main(const float* __restrict__ off,
              const float* __restrict__ msk,
              const ushort* __restrict__ xt,   // f16 (B,DG,H,W,Cg)
              const ushort* __restrict__ wt,   // f16 [o][(g*9+k)*16+cg]
              const float* __restrict__ bias,
              float* __restrict__ out) {
  __shared__ __align__(16) ushort S[TP * ROWP];        // 37,888 B -> 4 blocks/CU

  const int tid  = threadIdx.x;
  const int pos0 = blockIdx.x * TP;
  const int b    = pos0 >> 14;
  const int ho   = (pos0 >> 7) & 127;
  const int wo0  = pos0 & 127;

  const int lane = tid & 63;
  const int wv   = tid >> 6;
  const int l15  = lane & 15;
  const int kq   = lane >> 4;

  const float* offB = off + (size_t)b * 144 * NHW + ho * NW + wo0;
  const float* mskB = msk + (size_t)b * 72  * NHW + ho * NW + wo0;

  f32x4 acc[4][2];
#pragma unroll
  for (int m = 0; m < 4; ++m) {
    acc[m][0] = {0.f, 0.f, 0.f, 0.f};
    acc[m][1] = {0.f, 0.f, 0.f, 0.f};
  }

  for (int ch = 0; ch < 4; ++ch) {
    if (ch) __syncthreads();               // previous MFMA done reading S

    // ---- Phase A: sample chunk ch (groups 2ch, 2ch+1) ----
#pragma unroll
    for (int it = 0; it < 5; ++it) {
      const int t = tid + it * 256;
      if (t < TP * 18) {
        const int p  = t & 63;
        const int j  = t >> 6;             // 0..17
        const int gl = j / 9;
        const int k  = j - gl * 9;
        const int g  = ch * 2 + gl;
        const int gk = g * 9 + k;
        const int ky = k / 3, kx = k - ky * 3;
        const int wo = wo0 + p;

        const float dy = offB[(gk * 2) * NHW + p];
        const float dx = offB[(gk * 2 + 1) * NHW + p];
        const float mm = mskB[gk * NHW + p];

        const float sy = dy + (float)(ho - 1 + ky);
        const float sx = dx + (float)(wo - 1 + kx);
        const float y0f = floorf(sy), x0f = floorf(sx);
        const float ly = sy - y0f, lx = sx - x0f;
        const int y0 = (int)y0f, x0 = (int)x0f;
        const int y1 = y0 + 1,  x1 = x0 + 1;
        const float hy = 1.f - ly, hx = 1.f - lx;

        float w00 = hy * hx * mm, w01 = hy * lx * mm;
        float w10 = ly * hx * mm, w11 = ly * lx * mm;
        if (y0 < 0 || y0 >= NH) { w00 = 0.f; w01 = 0.f; }
        if (y1 < 0 || y1 >= NH) { w10 = 0.f; w11 = 0.f; }
        if (x0 < 0 || x0 >= NW) { w00 = 0.f; w10 = 0.f; }
        if (x1 < 0 || x1 >= NW) { w01 = 0.f; w11 = 0.f; }

        const int yc0 = min(max(y0, 0), NH - 1);
        const int yc1 = min(max(y1, 0), NH - 1);
        const int xc0 = min(max(x0, 0), NW - 1);
        const int xc1 = min(max(x1, 0), NW - 1);

        const ushort* xg = xt + (size_t)(b * NDG + g) * NHW * NCG;
        const uint4* q00 = (const uint4*)(xg + (yc0 * NW + xc0) * NCG);
        const uint4* q01 = (const uint4*)(xg + (yc0 * NW + xc1) * NCG);
        const uint4* q10 = (const uint4*)(xg + (yc1 * NW + xc0) * NCG);
        const uint4* q11 = (const uint4*)(xg + (yc1 * NW + xc1) * NCG);

        C16 v00, v01, v10, v11, r;
        v00.u[0] = q00[0]; v00.u[1] = q00[1];
        v01.u[0] = q01[0]; v01.u[1] = q01[1];
        v10.u[0] = q10[0]; v10.u[1] = q10[1];
        v11.u[0] = q11[0]; v11.u[1] = q11[1];

        const __half2 W00 = __float2half2_rn(w00);
        const __half2 W01 = __float2half2_rn(w01);
        const __half2 W10 = __float2half2_rn(w10);
        const __half2 W11 = __float2half2_rn(w11);
#pragma unroll
        for (int i = 0; i < 8; ++i) {
          __half2 a = __hmul2(v00.h[i], W00);
          a = __hfma2(v01.h[i], W01, a);
          a = __hfma2(v10.h[i], W10, a);
          a = __hfma2(v11.h[i], W11, a);
          r.h[i] = a;
        }
        ushort* dp = &S[p * ROWP + j * 16];
        *(uint4*)dp = r.u[0];
        *((uint4*)dp + 1) = r.u[1];
      }
    }
    __syncthreads();

    // ---- Phase B: MFMA over this chunk's K=288 ----
    const ushort* bw0 = wt + (size_t)(wv * 32 + l15) * NCK + ch * BKC + kq * 8;
    const ushort* bw1 = bw0 + 16 * NCK;
    const ushort* sa  = &S[l15 * ROWP + kq * 8];
#pragma unroll 3
    for (int kk = 0; kk < BKC; kk += 32) {
      const half8 b0 = *(const half8*)(bw0 + kk);
      const half8 b1 = *(const half8*)(bw1 + kk);
#pragma unroll
      for (int m = 0; m < 4; ++m) {
        const half8 a = *(const half8*)(sa + m * 16 * ROWP + kk);
        acc[m][0] = __builtin_amdgcn_mfma_f32_16x16x32_f16(a, b0, acc[m][0], 0, 0, 0);
        acc[m][1] = __builtin_amdgcn_mfma_f32_16x16x32_f16(a, b1, acc[m][1], 0, 0, 0);
      }
    }
  }

  // ---- epilogue: D col = l15 (cout), row = kq*4+reg within M-subtile ----
#pragma unroll
  for (int n = 0; n < 2; ++n) {
    const int c0 = wv * 32 + n * 16 + l15;
    const float bs = bias[c0];
    float* op = out + (size_t)(b * NCOUT + c0) * NHW + ho * NW + wo0 + kq * 4;
#pragma unroll
    for (int m = 0; m < 4; ++m) {
      float4 r = {acc[m][n][0] + bs, acc[m][n][1] + bs,
                  acc[m][n][2] + bs, acc[m][n][3] + bs};
      *(float4*)(op + m * 16) = r;
    }
  }
}

extern "C" void kernel_launch(void* const* d_in, const int* in_sizes, int n_in,
                              void* d_out, int out_size, void* d_ws, size_t ws_size,
                              hipStream_t stream) {
  const float* x    = (const float*)d_in[0];
  const float* off  = (const float*)d_in[1];
  const float* msk  = (const float*)d_in[2];
  const float* wgt  = (const float*)d_in[3];
  const float* bias = (const float*)d_in[4];
  float* out = (float*)d_out;

  ushort* xt = (ushort*)d_ws;                          // 16,777,216 B
  ushort* wf = xt + (size_t)NB * NDG * NHW * NCG;      // +294,912 B

  hipLaunchKernelGGL(prep, dim3(640), dim3(256), 0, stream, x, wgt, xt, wf);
  hipLaunchKernelGGL(dcn_main, dim3((NB * NH * NW) / TP), dim3(256), 0, stream,
                     off, msk, xt, wf, bias, out);
}

// Round 6
// 188.444 us; speedup vs baseline: 1.5455x; 1.0825x over previous
//
#include <hip/hip_runtime.h>
#include <hip/hip_fp16.h>

// ModulatedDeformConv (DCNv2) — f16 MFMA, M=128 row-tile, 2 dispatches.
// B=4, C=128, H=W=128, Cout=128, DG=8 (Cg=16), 3x3, stride=1, pad=1, dil=1.
//
// prep (R4-proven): blocks 0-127: weight fp32 [o][c*9+k] -> f16
//   wf[o][g*160 + k*16 + cg] (K-pad [144,160)=0); blocks 128-639: x fp32
//   (B,C,H,W) -> f16 x_t (B,DG,H,W,Cg) via LDS stride-9 transpose.
// dcn_main: 512 blocks x 512 thr; block = one output row (b,ho):
//   M=128 positions x N=128 couts. 8 chunks (1 deform group, K=160 padded):
//   sample S[128][160] f16 into LDS (row stride 168 f16), then 5 ksteps of
//   mfma_f32_16x16x32_f16; wave wv owns couts [wv*16,wv*16+16) x 8 M-subtiles.

#define NB    4
#define NC    128
#define NH    128
#define NW    128
#define NCOUT 128
#define NDG   8
#define NCG   16
#define NK    9
#define NCK   1152
#define NHW   16384
#define GK    160            // padded K per group
#define ROWP  168            // S row stride in f16 (336 B, 16B-aligned)
#define WROW  1280           // wf row stride in f16 (8*160)

typedef __attribute__((ext_vector_type(4))) float f32x4;
typedef _Float16 half8 __attribute__((ext_vector_type(8)));

union C16 { uint4 u[2]; __half2 h[8]; };

__device__ __forceinline__ unsigned pk2h(float a, float b) {
  return (unsigned)__half_as_ushort(__float2half_rn(a)) |
         ((unsigned)__half_as_ushort(__float2half_rn(b)) << 16);
}

// ---------------- fused prep (R4 structure) ----------------
__global__ __launch_bounds__(256)
void prep(const float* __restrict__ x, const float* __restrict__ w,
          ushort* __restrict__ xt, ushort* __restrict__ wf) {
  __shared__ __align__(16) unsigned LDSU[1024 * 9];   // 36,864 B
  const int tid = threadIdx.x;

  if (blockIdx.x < 128) {
    // ---- weight permute: [o][c*9+k] -> [o][g*160+k*16+cg] (f16, padded) ----
    const int o = blockIdx.x;
    float* WL = (float*)LDSU;                          // 1152 floats
    const float4* src = (const float4*)(w + o * NCK);
    for (int i = tid; i < NCK / 4; i += 256) ((float4*)WL)[i] = src[i];
    __syncthreads();
    unsigned* dst = (unsigned*)wf + o * (WROW / 2);
    for (int t = tid; t < WROW / 2; t += 256) {
      const int g = t / 80, r = t - g * 80;
      unsigned v = 0;
      if (r < 72) {
        const int k = r >> 3;
        const int c = g * NCG + (r & 7) * 2;
        v = pk2h(WL[c * NK + k], WL[(c + 1) * NK + k]);
      }
      dst[t] = v;
    }
  } else {
    // ---- x transpose: (B,C,H,W) fp32 -> (B,DG,H,W,Cg) f16 ----
    const int blk  = blockIdx.x - 128;                 // 0..511
    const int slab = blk >> 4;                         // b*8+g
    const int hw0  = (blk & 15) * 1024;
    const float* xb = x + (size_t)slab * NCG * NHW + hw0;
#pragma unroll
    for (int cp = 0; cp < 8; ++cp) {
#pragma unroll
      for (int i = 0; i < 4; ++i) {
        const int hw = tid + 256 * i;
        LDSU[hw * 9 + cp] =
            pk2h(xb[(2 * cp) * NHW + hw], xb[(2 * cp + 1) * NHW + hw]);
      }
    }
    __syncthreads();
    uint4* dst = (uint4*)(xt + ((size_t)slab * NHW + hw0) * NCG);
#pragma unroll
    for (int j = 0; j < 8; ++j) {
      const int lin = tid + 256 * j;
      const int hw = lin >> 1, q = lin & 1;
      uint4 v;
      v.x = LDSU[hw * 9 + q * 4 + 0];
      v.y = LDSU[hw * 9 + q * 4 + 1];
      v.z = LDSU[hw * 9 + q * 4 + 2];
      v.w = LDSU[hw * 9 + q * 4 + 3];
      dst[lin] = v;
    }
  }
}

// ---------------- main ----------------
__device__ __forceinline__ void sample_one(
    int t, int g, int b, int ho, float dy, float dx, float mm,
    const ushort* __restrict__ xt, ushort* __restrict__ S) {
  const int p  = t & 127;                // wo
  const int k  = t >> 7;                 // 0..8
  const int ky = k / 3, kx = k - ky * 3;

  const float sy = dy + (float)(ho - 1 + ky);
  const float sx = dx + (float)(p - 1 + kx);
  const float y0f = floorf(sy), x0f = floorf(sx);
  const float ly = sy - y0f, lx = sx - x0f;
  const int y0 = (int)y0f, x0 = (int)x0f;
  const int y1 = y0 + 1,  x1 = x0 + 1;
  const float hy = 1.f - ly, hx = 1.f - lx;

  float w00 = hy * hx * mm, w01 = hy * lx * mm;
  float w10 = ly * hx * mm, w11 = ly * lx * mm;
  if (y0 < 0 || y0 >= NH) { w00 = 0.f; w01 = 0.f; }
  if (y1 < 0 || y1 >= NH) { w10 = 0.f; w11 = 0.f; }
  if (x0 < 0 || x0 >= NW) { w00 = 0.f; w10 = 0.f; }
  if (x1 < 0 || x1 >= NW) { w01 = 0.f; w11 = 0.f; }

  const int yc0 = min(max(y0, 0), NH - 1);
  const int yc1 = min(max(y1, 0), NH - 1);
  const int xc0 = min(max(x0, 0), NW - 1);
  const int xc1 = min(max(x1, 0), NW - 1);

  const ushort* xg = xt + (size_t)(b * NDG + g) * NHW * NCG;
  const uint4* q00 = (const uint4*)(xg + (yc0 * NW + xc0) * NCG);
  const uint4* q01 = (const uint4*)(xg + (yc0 * NW + xc1) * NCG);
  const uint4* q10 = (const uint4*)(xg + (yc1 * NW + xc0) * NCG);
  const uint4* q11 = (const uint4*)(xg + (yc1 * NW + xc1) * NCG);

  C16 v00, v01, v10, v11, r;
  v00.u[0] = q00[0]; v00.u[1] = q00[1];
  v01.u[0] = q01[0]; v01.u[1] = q01[1];
  v10.u[0] = q10[0]; v10.u[1] = q10[1];
  v11.u[0] = q11[0]; v11.u[1] = q11[1];

  const __half2 W00 = __float2half2_rn(w00);
  const __half2 W01 = __float2half2_rn(w01);
  const __half2 W10 = __float2half2_rn(w10);
  const __half2 W11 = __float2half2_rn(w11);
#pragma unroll
  for (int i = 0; i < 8; ++i) {
    __half2 a = __hmul2(v00.h[i], W00);
    a = __hfma2(v01.h[i], W01, a);
    a = __hfma2(v10.h[i], W10, a);
    a = __hfma2(v11.h[i], W11, a);
    r.h[i] = a;
  }
  ushort* dp = &S[p * ROWP + k * 16];
  *(uint4*)dp = r.u[0];
  *((uint4*)dp + 1) = r.u[1];
}

__global__ __launch_bounds__(512, 4)
void dcn_main(const float* __restrict__ off,
              const float* __restrict__ msk,
              const ushort* __restrict__ xt,   // f16 (B,DG,H,W,Cg)
              const ushort* __restrict__ wf,   // f16 [o][g*160+k*16+cg]
              const float* __restrict__ bias,
              float* __restrict__ out) {
  __shared__ __align__(16) ushort S[128 * ROWP];   // 43,008 B

  const int tid = threadIdx.x;
  const int blk = blockIdx.x;                      // 0..511
  const int b   = blk >> 7;
  const int ho  = blk & 127;

  const int lane = tid & 63;
  const int wv   = tid >> 6;                       // 0..7 = n-subtile
  const int l15  = lane & 15;
  const int kq   = lane >> 4;

  const float* offB = off + (size_t)b * 144 * NHW + ho * NW;
  const float* mskB = msk + (size_t)b * 72  * NHW + ho * NW;

  // zero the K-pad region: f16 cols [144,160) of each of 128 rows
  for (int i = tid; i < 128 * 8; i += 512) {
    ((unsigned*)S)[(i >> 3) * (ROWP / 2) + 72 + (i & 7)] = 0;
  }
  __syncthreads();

  f32x4 acc[8];
#pragma unroll
  for (int m = 0; m < 8; ++m) acc[m] = {0.f, 0.f, 0.f, 0.f};

  const int t0 = tid;            // tasks: 1152 = 512 + 512 + 128
  const int t1 = tid + 512;
  const int t2 = tid + 1024;
  const int p0 = t0 & 127, k0 = t0 >> 7;
  const int p1 = t1 & 127, k1 = t1 >> 7;
  const int p2 = t2 & 127, k2 = t2 >> 7;

  for (int g = 0; g < 8; ++g) {
    if (g) __syncthreads();                        // MFMA(g-1) done with S

    // ---- Phase A: offsets first (flat chain), then gather+combine ----
    const int gk0 = g * 9 + k0, gk1 = g * 9 + k1, gk2 = g * 9 + k2;
    const float dy0 = offB[(gk0 * 2) * NHW + p0];
    const float dx0 = offB[(gk0 * 2 + 1) * NHW + p0];
    const float m0  = mskB[gk0 * NHW + p0];
    const float dy1 = offB[(gk1 * 2) * NHW + p1];
    const float dx1 = offB[(gk1 * 2 + 1) * NHW + p1];
    const float m1  = mskB[gk1 * NHW + p1];
    float dy2 = 0.f, dx2 = 0.f, m2 = 0.f;
    if (tid < 128) {
      dy2 = offB[(gk2 * 2) * NHW + p2];
      dx2 = offB[(gk2 * 2 + 1) * NHW + p2];
      m2  = mskB[gk2 * NHW + p2];
    }
    sample_one(t0, g, b, ho, dy0, dx0, m0, xt, S);
    sample_one(t1, g, b, ho, dy1, dx1, m1, xt, S);
    if (tid < 128) sample_one(t2, g, b, ho, dy2, dx2, m2, xt, S);
    __syncthreads();

    // ---- Phase B: 5 ksteps of mfma_f32_16x16x32_f16 ----
    const ushort* bw = wf + (size_t)(wv * 16 + l15) * WROW + g * GK + kq * 8;
    const ushort* sa = &S[l15 * ROWP + kq * 8];
#pragma unroll
    for (int ks = 0; ks < 5; ++ks) {
      const half8 bfrag = *(const half8*)(bw + ks * 32);
#pragma unroll
      for (int m = 0; m < 8; ++m) {
        const half8 a = *(const half8*)(sa + m * 16 * ROWP + ks * 32);
        acc[m] = __builtin_amdgcn_mfma_f32_16x16x32_f16(a, bfrag, acc[m], 0, 0, 0);
      }
    }
  }

  // ---- epilogue: D col = l15 (cout), row = kq*4+reg = wo within subtile ----
  const int c0 = wv * 16 + l15;
  const float bs = bias[c0];
  float* op = out + (size_t)(b * NCOUT + c0) * NHW + ho * NW + kq * 4;
#pragma unroll
  for (int m = 0; m < 8; ++m) {
    float4 r = {acc[m][0] + bs, acc[m][1] + bs, acc[m][2] + bs, acc[m][3] + bs};
    *(float4*)(op + m * 16) = r;
  }
}

extern "C" void kernel_launch(void* const* d_in, const int* in_sizes, int n_in,
                              void* d_out, int out_size, void* d_ws, size_t ws_size,
                              hipStream_t stream) {
  const float* x    = (const float*)d_in[0];
  const float* off  = (const float*)d_in[1];
  const float* msk  = (const float*)d_in[2];
  const float* wgt  = (const float*)d_in[3];
  const float* bias = (const float*)d_in[4];
  float* out = (float*)d_out;

  ushort* xt = (ushort*)d_ws;                          // 16,777,216 B
  ushort* wf = xt + (size_t)NB * NDG * NHW * NCG;      // +327,680 B

  hipLaunchKernelGGL(prep, dim3(640), dim3(256), 0, stream, x, wgt, xt, wf);
  hipLaunchKernelGGL(dcn_main, dim3(512), dim3(512), 0, stream,
                     off, msk, xt, wf, bias, out);
}